// Round 16
// baseline (492.139 us; speedup 1.0000x reference)
//
#include <hip/hip_runtime.h>
#include <hip/hip_bf16.h>
#include <cmath>

// Inputs/outputs float32. Geometry/sampling fp32 (k0/k1/k2). nf + rt chains as
// bf16 MFMA GEMMs (fp32 accum), LN fused into A-staging. Round 16: nf_front
// fuses x2->W0 GEMM->LN->qkv GEMM->attention->o-proj(+h0 reg-resid)->x1 per
// 32-row tile. h0 lives in registers + LDS only (W0/o-proj epilogues share
// strip-32 fragment ownership); LDS stays 39.4 KB -> 4 blocks/CU (unlike r14's
// full fusion which hit VGPR 128 / 3 blocks and regressed). nf_f1f2 unchanged.

using bf16 = __hip_bfloat16;
#define DEV __device__ __forceinline__

typedef __attribute__((ext_vector_type(8))) short short8;
typedef __attribute__((ext_vector_type(4))) float f32x4;

DEV float s2f(short s){ unsigned u=((unsigned)(unsigned short)s)<<16; float f; __builtin_memcpy(&f,&u,4); return f; }
DEV short f2s(float f){ bf16 h=__float2bfloat16(f); short r; __builtin_memcpy(&r,&h,2); return r; }

constexpr int NRAY=256, SP=64, SI=32, S=96, KHR=8, CIN=32, C=128, NH=8, DH=16;
constexpr int NT = NRAY*S;           // 24576 tokens
constexpr int MTOT = NT*KHR;         // 196608 rows in the nf chain

// ---- fp32 ws region (element offsets) ----
constexpr size_t OFF_RI=0, OFF_TR=9, OFF_M=16, OFF_TN=272, OFF_TF=528, OFF_RDO=784,
  OFF_TS=1552, OFF_OCCS=26128, OFF_OCCT=50704, OFF_CRD=75280, OFF_XS=149008, F32_CNT=935440;

// ---- bf16 ws region (element offsets from bf16 base) ----
constexpr size_t WT_W0=0, WT_NQKV=8192, WT_NO=57344, WT_NF1=73728, WT_NF2=106496,
  WT_RQKV=139264, WT_RO=188416, WT_RF1=204800, WT_RF2=237568, WT_TOT=270336;
constexpr size_t H2OFF=WT_TOT;                 // h2: NT*128
constexpr size_t CHB=H2OFF+(size_t)NT*128;     // chunk / rt arena base
constexpr size_t RT_TOT=(size_t)NT*512;        // compacted rt arena

struct Corn { int off[8]; float wz, wy, wx; };

DEV void make_corners(float cz, float cy, float cx, Corn& Cn){
  cz=fminf(fmaxf(cz,0.f),31.f); cy=fminf(fmaxf(cy,0.f),31.f); cx=fminf(fmaxf(cx,0.f),31.f);
  int z0=(int)cz, y0=(int)cy, x0=(int)cx;
  int z1=(z0+1<31)?z0+1:31, y1=(y0+1<31)?y0+1:31, x1=(x0+1<31)?x0+1:31;
  Cn.wz=cz-(float)z0; Cn.wy=cy-(float)y0; Cn.wx=cx-(float)x0;
  int zy00=z0*1024+y0*32, zy01=z0*1024+y1*32, zy10=z1*1024+y0*32, zy11=z1*1024+y1*32;
  Cn.off[0]=zy00+x0; Cn.off[1]=zy00+x1;
  Cn.off[2]=zy01+x0; Cn.off[3]=zy01+x1;
  Cn.off[4]=zy10+x0; Cn.off[5]=zy10+x1;
  Cn.off[6]=zy11+x0; Cn.off[7]=zy11+x1;
}

DEV float interp1(const float* __restrict__ vol, const Corn& Cn){
  float v000=vol[Cn.off[0]], v001=vol[Cn.off[1]];
  float v010=vol[Cn.off[2]], v011=vol[Cn.off[3]];
  float v100=vol[Cn.off[4]], v101=vol[Cn.off[5]];
  float v110=vol[Cn.off[6]], v111=vol[Cn.off[7]];
  float wx=Cn.wx, wy=Cn.wy, wz=Cn.wz;
  float c00=v000*(1.f-wx)+v001*wx, c01=v010*(1.f-wx)+v011*wx;
  float c10=v100*(1.f-wx)+v101*wx, c11=v110*(1.f-wx)+v111*wx;
  return (c00*(1.f-wy)+c01*wy)*(1.f-wz) + (c10*(1.f-wy)+c11*wy)*wz;
}

DEV float ray_box(const float* Ri, const float* tr, const float* o3, const float* d3, const float* half){
  float tlo=-INFINITY, thi=INFINITY;
  for(int j=0;j<3;j++){
    float oo=Ri[j*3+0]*o3[0]+Ri[j*3+1]*o3[1]+Ri[j*3+2]*o3[2]+tr[j];
    float dd=Ri[j*3+0]*d3[0]+Ri[j*3+1]*d3[1]+Ri[j*3+2]*d3[2];
    if (fabsf(dd)<1e-9f) dd=1e-9f;
    float inv=1.f/dd;
    float t0=(-half[j]-oo)*inv, t1=(half[j]-oo)*inv;
    tlo=fmaxf(tlo,fminf(t0,t1)); thi=fminf(thi,fmaxf(t0,t1));
  }
  bool valid = thi >= fmaxf(tlo,0.f);
  return valid ? tlo : INFINITY;
}

// ============================= k0: pose inverse + ray-box =============================
__global__ __launch_bounds__(64) void k0_setup(
  const float* __restrict__ rays_o, const float* __restrict__ rays_d,
  const float* __restrict__ pose, const float* __restrict__ dimv,
  float* __restrict__ wsf)
{
  __shared__ float Ri[9], tr[3];
  int tid=threadIdx.x; int ray=blockIdx.x*64+tid;
  if(tid==0){
    float P[16];
    for(int j=0;j<16;j++) P[j]=pose[j];
    float a00=P[0],a01=P[1],a02=P[2],a10=P[4],a11=P[5],a12=P[6],a20=P[8],a21=P[9],a22=P[10];
    float c00=a11*a22-a12*a21, c01=a12*a20-a10*a22, c02=a10*a21-a11*a20;
    float det=a00*c00+a01*c01+a02*c02;
    float id=1.f/det;
    Ri[0]=c00*id; Ri[1]=(a02*a21-a01*a22)*id; Ri[2]=(a01*a12-a02*a11)*id;
    Ri[3]=c01*id; Ri[4]=(a00*a22-a02*a20)*id; Ri[5]=(a02*a10-a00*a12)*id;
    Ri[6]=c02*id; Ri[7]=(a01*a20-a00*a21)*id; Ri[8]=(a00*a11-a01*a10)*id;
    float t0=P[3],t1=P[7],t2=P[11];
    tr[0]=-(Ri[0]*t0+Ri[1]*t1+Ri[2]*t2);
    tr[1]=-(Ri[3]*t0+Ri[4]*t1+Ri[5]*t2);
    tr[2]=-(Ri[6]*t0+Ri[7]*t1+Ri[8]*t2);
    if(blockIdx.x==0){
      for(int j=0;j<9;j++) wsf[OFF_RI+j]=Ri[j];
      for(int j=0;j<3;j++) wsf[OFF_TR+j]=tr[j];
    }
  }
  __syncthreads();
  float o3[3],d3[3],dim[3],half[3];
  for(int j=0;j<3;j++){ o3[j]=rays_o[ray*3+j]; d3[j]=rays_d[ray*3+j];
                        dim[j]=dimv[j]; half[j]=0.5f*dim[j]; }
  float tnear=ray_box(Ri,tr,o3,d3,half);
  float tmax=tnear+10.f*(fabsf(dim[0])+fabsf(dim[1])+fabsf(dim[2]));
  float pm[3]={o3[0]+tmax*d3[0], o3[1]+tmax*d3[1], o3[2]+tmax*d3[2]};
  float nd[3]={-d3[0],-d3[1],-d3[2]};
  float tfar=tmax-ray_box(Ri,tr,pm,nd,half);
  bool mm = isfinite(tnear)&&isfinite(tfar)&&(tfar>tnear);
  wsf[OFF_M+ray]=mm?1.f:0.f;
  wsf[OFF_TN+ray]=mm?tnear:0.f;
  wsf[OFF_TF+ray]=mm?tfar:1.f;
  for(int j=0;j<3;j++)
    wsf[OFF_RDO+(size_t)ray*3+j]=Ri[j*3+0]*d3[0]+Ri[j*3+1]*d3[1]+Ri[j*3+2]*d3[2];
}

// ============================= k1: sampling + interp + stable sort =============================
__global__ __launch_bounds__(128) void k1_sample(
  const float* __restrict__ rays_o, const float* __restrict__ rays_d, const float* __restrict__ dimv,
  const float* __restrict__ voxel, const float* __restrict__ fvol,
  const float* __restrict__ u_p, const float* __restrict__ u_cat, const float* __restrict__ u_lam,
  float* __restrict__ wsf)
{
  int i=blockIdx.x, tid=threadIdx.x;
  __shared__ float Ri[9], tr[3], dim[3], o3[3], d3[3];
  __shared__ float t_all[S], occ_all[S], crd_sh[S][3];
  __shared__ int   coff[S][8];
  __shared__ float cww[S][3];
  __shared__ float cdf[SP];
  __shared__ float totv;
  __shared__ int   rnk[S];
  if(tid<9) Ri[tid]=wsf[OFF_RI+tid];
  if(tid<3){ tr[tid]=wsf[OFF_TR+tid]; dim[tid]=dimv[tid];
             o3[tid]=rays_o[i*3+tid]; d3[tid]=rays_d[i*3+tid]; }
  __syncthreads();
  float tn=wsf[OFF_TN+i], tf=wsf[OFF_TF+i];

  auto do_sample=[&](int s, float t){
    float px=o3[0]+t*d3[0], py=o3[1]+t*d3[1], pz=o3[2]+t*d3[2];
    float q0=Ri[0]*px+Ri[1]*py+Ri[2]*pz+tr[0];
    float q1=Ri[3]*px+Ri[4]*py+Ri[5]*pz+tr[1];
    float q2=Ri[6]*px+Ri[7]*py+Ri[8]*pz+tr[2];
    float cz=(0.5f+q2/dim[2])*31.f;
    float cy=(0.5f+q1/dim[1])*31.f;
    float cx=(0.5f+q0/dim[0])*31.f;
    crd_sh[s][0]=cz; crd_sh[s][1]=cy; crd_sh[s][2]=cx;
    Corn Cn; make_corners(cz,cy,cx,Cn);
    for(int q=0;q<8;q++) coff[s][q]=Cn.off[q];
    cww[s][0]=Cn.wz; cww[s][1]=Cn.wy; cww[s][2]=Cn.wx;
    occ_all[s]=interp1(voxel,Cn);
    t_all[s]=t;
  };

  if(tid<SP){
    float u=u_p[i*SP+tid];
    float t=tn+(tf-tn)*((float)tid+u)*(1.f/64.f);
    do_sample(tid,t);
  }
  __syncthreads();
  if(tid==0){
    float c=0;
    for(int j=0;j<SP-1;j++){ float pr=occ_all[j]+occ_all[j+1]; pr=fmaxf(pr,1e-12f); c+=pr; cdf[j]=c; }
    totv=c;
  }
  __syncthreads();
  if(tid<SP-1) cdf[tid]=cdf[tid]/totv;
  __syncthreads();
  if(tid<SI){
    float u=u_cat[i*SI+tid];
    int cnt=0;
    for(int j=0;j<SP-1;j++) cnt += (u>=cdf[j])?1:0;
    int ind=(cnt<SP-2)?cnt:(SP-2);
    float lam=u_lam[i*SI+tid];
    float tfine=lam*t_all[ind]+(1.f-lam)*t_all[ind+1];
    do_sample(SP+tid,tfine);
  }
  __syncthreads();
  if(tid<S){  // stable counting-rank sort (== stable argsort)
    float ts=t_all[tid]; int r=0;
    for(int j=0;j<S;j++){ float tj=t_all[j]; r += (tj<ts || (tj==ts && j<tid)) ? 1:0; }
    rnk[tid]=r;
    size_t base=(size_t)i*S+r;
    wsf[OFF_TS+base]=ts;
    wsf[OFF_OCCS+base]=occ_all[tid];
    wsf[OFF_CRD+base*3+0]=crd_sh[tid][0];
    wsf[OFF_CRD+base*3+1]=crd_sh[tid][1];
    wsf[OFF_CRD+base*3+2]=crd_sh[tid][2];
  }
  __syncthreads();
  for(int idx=tid; idx<S*CIN; idx+=128){
    int s=idx>>5, c=idx&31;
    float wz=cww[s][0], wy=cww[s][1], wx=cww[s][2];
    const float* vc=fvol+(size_t)c*32768;
    float v000=vc[coff[s][0]], v001=vc[coff[s][1]];
    float v010=vc[coff[s][2]], v011=vc[coff[s][3]];
    float v100=vc[coff[s][4]], v101=vc[coff[s][5]];
    float v110=vc[coff[s][6]], v111=vc[coff[s][7]];
    float c00=v000*(1.f-wx)+v001*wx, c01=v010*(1.f-wx)+v011*wx;
    float c10=v100*(1.f-wx)+v101*wx, c11=v110*(1.f-wx)+v111*wx;
    float val=(c00*(1.f-wy)+c01*wy)*(1.f-wz)+(c10*(1.f-wy)+c11*wy)*wz;
    wsf[OFF_XS+((size_t)i*S+rnk[s])*CIN+c]=val;
  }
}

// ============================= k2: sigma MLP, alpha, outputs 0..2 =============================
__global__ __launch_bounds__(128) void k2_sigma(
  const float* __restrict__ dW1, const float* __restrict__ db1,
  const float* __restrict__ dW2, const float* __restrict__ db2,
  float* __restrict__ wsf, float* __restrict__ out)
{
  int t=blockIdx.x, tid=threadIdx.x, i=t/S;
  __shared__ float xx[33];
  __shared__ float part[2];
  if(tid<32) xx[tid]=wsf[OFF_XS+(size_t)t*32+tid];
  if(tid==32) xx[32]=wsf[OFF_OCCS+t];
  __syncthreads();
  float acc=db1[tid];
  for(int k=0;k<33;k++) acc=fmaf(xx[k], dW1[k*C+tid], acc);
  acc = acc>=0.f?acc:0.01f*acc;
  float g = acc*dW2[tid];
  for(int off=32;off;off>>=1) g+=__shfl_down(g,off,64);
  if((tid&63)==0) part[tid>>6]=g;
  __syncthreads();
  if(tid==0){
    float z=part[0]+part[1]+db2[0];
    float sg=1.f/(1.f+expf(-z));
    float occ=xx[32];
    float occt=occ<0.7f?0.f:occ;
    float alpha=occt*sg;
    float m=wsf[OFF_M+i];
    float ts=wsf[OFF_TS+t];
    out[t]      =m!=0.f?ts:0.f;
    out[NT+t]   =m!=0.f?alpha:0.f;
    out[2*NT+t] =m!=0.f?occt:0.f;
    wsf[OFF_OCCT+t]=occt;
  }
}

// ============================= weight prep: fp32 KxN -> bf16 N x Kpad (B^T) =============================
__global__ __launch_bounds__(256) void k_wprep(
  const float* __restrict__ w0, const float* __restrict__ nqkv, const float* __restrict__ no_,
  const float* __restrict__ nf1, const float* __restrict__ nf2,
  const float* __restrict__ rqkv, const float* __restrict__ ro_,
  const float* __restrict__ rf1, const float* __restrict__ rf2,
  short* __restrict__ WT)
{
  int gid = blockIdx.x*256+threadIdx.x;
  if(gid>=(int)WT_TOT) return;
  const float* src; int K,N,Kp; int base;
  if(gid<8192){src=w0;K=42;N=128;Kp=64;base=0;}
  else if(gid<57344){src=nqkv;K=128;N=384;Kp=128;base=8192;}
  else if(gid<73728){src=no_;K=128;N=128;Kp=128;base=57344;}
  else if(gid<106496){src=nf1;K=128;N=256;Kp=128;base=73728;}
  else if(gid<139264){src=nf2;K=256;N=128;Kp=256;base=106496;}
  else if(gid<188416){src=rqkv;K=128;N=384;Kp=128;base=139264;}
  else if(gid<204800){src=ro_;K=128;N=128;Kp=128;base=188416;}
  else if(gid<237568){src=rf1;K=128;N=256;Kp=128;base=204800;}
  else {src=rf2;K=256;N=128;Kp=256;base=237568;}
  int local=gid-base; int n=local/Kp, k=local%Kp;
  WT[gid] = (k<K)? f2s(src[(size_t)k*N+n]) : (short)0;
}

// ============================= xx2 builder: 4 tokens/block =============================
__global__ __launch_bounds__(256) void k_build(
  const float* __restrict__ fvhr, const float* __restrict__ wsf,
  short* __restrict__ X2, int tok0)
{
  int tid=threadIdx.x; int sub=tid>>6, stid=tid&63;
  int tloc=blockIdx.x*4+sub;
  int t=tok0+tloc, i=t/S;
  __shared__ float hr[4][KHR][6];
  __shared__ float xf[4][32];
  __shared__ float RiS[9];
  __shared__ float geo[4][4];
  __shared__ float crd[4][3];
  if(tid<9) RiS[tid]=wsf[OFF_RI+tid];
  if(stid>=16&&stid<19) crd[sub][stid-16]=wsf[OFF_CRD+(size_t)t*3+(stid-16)];
  if(stid>=32) xf[sub][stid-32]=wsf[OFF_XS+(size_t)t*32+(stid-32)];
  if(stid==9) geo[sub][0]=wsf[OFF_OCCT+t];
  if(stid>=12&&stid<15) geo[sub][1+(stid-12)]=wsf[OFF_RDO+(size_t)i*3+(stid-12)];
  __syncthreads();
  if(stid<48){
    int k=stid/6, ch=stid%6;
    Corn Cn; make_corners(crd[sub][0],crd[sub][1],crd[sub][2],Cn);
    hr[sub][k][ch]=interp1(fvhr+(size_t)(k*6+ch)*32768, Cn);
  }
  __syncthreads();
  for(int idx=stid; idx<512; idx+=64){
    int k=idx>>6, j=idx&63; float v;
    if(j<32) v=xf[sub][j];
    else if(j<35) v=hr[sub][k][j-32];
    else if(j<38){int r=j-35; v=hr[sub][k][3]*RiS[r*3+0]+hr[sub][k][4]*RiS[r*3+1]+hr[sub][k][5]*RiS[r*3+2];}
    else if(j<41) v=geo[sub][1+(j-38)];
    else if(j==41) v=geo[sub][0];
    else v=0.f;
    X2[(size_t)(tloc*8+k)*64 + j]=f2s(v);
  }
}

// ============================= MFMA GEMM: C = [LN?](A) @ Bt^T + bias [+lrelu] [+resid] =============================
template<int K, bool LNA, bool ACT, bool RESID>
__global__ __launch_bounds__(256) void gemm_ln(
  const short* __restrict__ A, const short* __restrict__ Bt,
  const float* __restrict__ bias, const short* __restrict__ Rres,
  short* __restrict__ Cg, int N)
{
  static_assert(!LNA || K==128, "LNA requires K==128");
  constexpr int KSA = (K<128)?K:128;
  constexpr int NSA = K/KSA;
  constexpr int LDA = KSA+8;
  constexpr int LDB = 64+8;
  __shared__ short Al[128*LDA];
  __shared__ short Bl[128*LDB];
  const int tid=threadIdx.x;
  const int bm=blockIdx.x*128, bn=blockIdx.y*128;
  const int lane=tid&63, wave=tid>>6;
  const int wm=(wave>>1)*64, wn=(wave&1)*64;
  const int quad=lane>>4, m16=lane&15;
  f32x4 acc[4][4];
  for(int a=0;a<4;a++) for(int b=0;b<4;b++) acc[a][b]=(f32x4){0.f,0.f,0.f,0.f};

  for(int sa=0; sa<NSA; ++sa){
    if(sa>0) __syncthreads();
    constexpr int CH8=KSA/8;
    for(int it=0; it<(128*CH8)/256; ++it){
      int li=it*256+tid; int row=li/CH8, kc=li%CH8;
      short8 v = *(const short8*)(A + (size_t)(bm+row)*K + sa*KSA + kc*8);
      if constexpr(LNA){
        float f[8]; float ls=0.f,lq=0.f;
        for(int e=0;e<8;e++){ f[e]=s2f(v[e]); ls+=f[e]; lq+=f[e]*f[e]; }
        for(int off=8;off;off>>=1){ ls+=__shfl_xor(ls,off,16); lq+=__shfl_xor(lq,off,16); }
        float mu=ls*(1.f/128.f);
        float var=lq*(1.f/128.f)-mu*mu;
        float rs=rsqrtf(var+1e-5f);
        for(int e=0;e<8;e++) v[e]=f2s((f[e]-mu)*rs);
      }
      *(short8*)&Al[row*LDA+kc*8]=v;
    }
    __syncthreads();
    for(int sb=0; sb<KSA/64; ++sb){
      if(sb>0) __syncthreads();
      for(int it=0; it<4; ++it){
        int li=it*256+tid; int row=li>>3, kc=li&7;
        *(short8*)&Bl[row*LDB+kc*8] =
          *(const short8*)(Bt + (size_t)(bn+row)*K + sa*KSA + sb*64 + kc*8);
      }
      __syncthreads();
      for(int kk=0; kk<64; kk+=32){
        int ka = sb*64+kk;
        short8 af[4], bfv[4];
        for(int im=0; im<4; im++)
          af[im] = *(const short8*)&Al[(wm+im*16+m16)*LDA + ka + quad*8];
        for(int in=0; in<4; in++)
          bfv[in] = *(const short8*)&Bl[(wn+in*16+m16)*LDB + kk + quad*8];
        for(int im=0;im<4;im++)
          for(int in=0;in<4;in++)
            acc[im][in] = __builtin_amdgcn_mfma_f32_16x16x32_bf16(af[im], bfv[in], acc[im][in], 0,0,0);
      }
    }
  }
  for(int in=0;in<4;in++){
    int col = bn + wn + in*16 + m16;
    float bv = bias[col];
    for(int im=0;im<4;im++){
      for(int r=0;r<4;r++){
        int grow = bm + wm + im*16 + quad*4 + r;
        float v = acc[im][in][r] + bv;
        if constexpr(ACT) v = v>=0.f? v : 0.01f*v;
        if constexpr(RESID) v += s2f(Rres[(size_t)grow*N + col]);
        Cg[(size_t)grow*N + col] = f2s(v);
      }
    }
  }
}

// ============================= nf_front: x2 -> W0 -> LN -> qkv -> attn -> o-proj(+h0) -> x1 ==
// 32 rows/block. h0 in regs+LDS only (strip-32 ownership shared by W0 and
// o-proj epilogues). LDS: Al 8704 + U 30720 = 39424 B -> 4 blocks/CU.
__global__ __launch_bounds__(256) void nf_front(
  const short* __restrict__ X2,
  const short* __restrict__ Bw0, const float* __restrict__ b0,
  const short* __restrict__ Btq, const float* __restrict__ bq,
  const short* __restrict__ Bto, const float* __restrict__ bo,
  short* __restrict__ X1)
{
  __shared__ short Al[32*136];
  __shared__ short U[15360];   // x2 2304 + Bw 5120 | Bl qkv 15360 | Qt 12544 | att 4352 + Wo 5120
  const int tid=threadIdx.x;
  const int bm=blockIdx.x*32;
  const int lane=tid&63, wave=tid>>6;
  const int quad=lane>>4, m16=lane&15;
  const int wns=wave*32;

  // ---- phase 0: stage x2 (32x64) into U[0..2304) stride 72
  {
    int row=tid>>3, kc=tid&7;
    *(short8*)&U[row*72+kc*8] = *(const short8*)(X2 + (size_t)(bm+row)*64 + kc*8);
  }
  short* Bw = U + 2304;
  // ---- phase 1: W0 GEMM (K=64, N=128, strip 32); h0 kept in regs
  f32x4 accA[2][2];
  for(int a=0;a<2;a++) for(int b=0;b<2;b++) accA[a][b]=(f32x4){0.f,0.f,0.f,0.f};
  for(int kc2=0;kc2<2;++kc2){
    __syncthreads();
    for(int it=0; it<2; ++it){
      int li=it*256+tid; int row=li>>2, c=li&3;
      *(short8*)&Bw[row*40+c*8] = *(const short8*)(Bw0 + (size_t)row*64 + kc2*32 + c*8);
    }
    __syncthreads();
    int ka=kc2*32;
    short8 af[2], bfv[2];
    af[0]=*(const short8*)&U[m16*72 + ka + quad*8];
    af[1]=*(const short8*)&U[(16+m16)*72 + ka + quad*8];
    for(int in=0;in<2;in++) bfv[in]=*(const short8*)&Bw[(wns+in*16+m16)*40 + quad*8];
    for(int im=0;im<2;im++) for(int in=0;in<2;in++)
      accA[im][in]=__builtin_amdgcn_mfma_f32_16x16x32_bf16(af[im],bfv[in],accA[im][in],0,0,0);
  }
  // h0 -> regs (bf16-rounded) + Al
  float h0r[2][2][4];
  for(int in=0;in<2;in++){
    int col=wns+in*16+m16;
    float bv=b0[col];
    for(int im=0;im<2;im++)
      for(int r=0;r<4;r++){
        short hv=f2s(accA[im][in][r]+bv);
        h0r[im][in][r]=s2f(hv);
        Al[(im*16+quad*4+r)*136+col]=hv;
      }
  }
  __syncthreads();
  // ---- phase 2: in-place LN of Al
  for(int it=0; it<2; ++it){
    int li=it*256+tid; int row=li>>4, kc=li&15;
    short8 v=*(short8*)&Al[row*136+kc*8];
    float f[8]; float ls=0.f,lq=0.f;
    for(int e=0;e<8;e++){ f[e]=s2f(v[e]); ls+=f[e]; lq+=f[e]*f[e]; }
    for(int off=8;off;off>>=1){ ls+=__shfl_xor(ls,off,16); lq+=__shfl_xor(lq,off,16); }
    float mu=ls*(1.f/128.f), var=lq*(1.f/128.f)-mu*mu, rs=rsqrtf(var+1e-5f);
    for(int e=0;e<8;e++) v[e]=f2s((f[e]-mu)*rs);
    *(short8*)&Al[row*136+kc*8]=v;
  }
  // ---- phase 3: qkv GEMM (A=Al, Bl=U)
  const int wn=wave*96;
  f32x4 acc6[2][6];
  for(int a=0;a<2;a++) for(int b=0;b<6;b++) acc6[a][b]=(f32x4){0.f,0.f,0.f,0.f};
  for(int kc2=0;kc2<4;++kc2){
    __syncthreads();
    for(int it=0; it<6; ++it){
      int li=it*256+tid; int row=li>>2, c=li&3;
      *(short8*)&U[row*40+c*8] = *(const short8*)(Btq + (size_t)row*128 + kc2*32 + c*8);
    }
    __syncthreads();
    int ka=kc2*32;
    short8 af[2], bfv[6];
    af[0]=*(const short8*)&Al[m16*136 + ka + quad*8];
    af[1]=*(const short8*)&Al[(16+m16)*136 + ka + quad*8];
    for(int in=0;in<6;in++) bfv[in]=*(const short8*)&U[(wn+in*16+m16)*40 + quad*8];
    for(int im=0;im<2;im++) for(int in=0;in<6;in++)
      acc6[im][in]=__builtin_amdgcn_mfma_f32_16x16x32_bf16(af[im],bfv[in],acc6[im][in],0,0,0);
  }
  __syncthreads();   // Bl reads drained before Qt overwrites U
  for(int in=0;in<6;in++){
    int col=wn+in*16+m16;
    float bv=bq[col];
    for(int im=0;im<2;im++)
      for(int r=0;r<4;r++)
        U[(im*16+quad*4+r)*392+col]=f2s(acc6[im][in][r]+bv);
  }
  __syncthreads();
  // ---- phase 4: attention (4 tok x 8 head x 8 q)
  int tok=tid>>6, h=(tid>>3)&7, q=tid&7;
  const short* base=&U[(tok*8)*392 + h*16];
  short8 q0v=*(const short8*)&base[q*392];
  short8 q1v=*(const short8*)&base[q*392+8];
  float qv[16];
  for(int e=0;e<8;e++){ qv[e]=s2f(q0v[e]); qv[8+e]=s2f(q1v[e]); }
  float sc[8]; float mx=-INFINITY;
  for(int j=0;j<8;j++){
    short8 k0=*(const short8*)&base[j*392+128];
    short8 k1=*(const short8*)&base[j*392+136];
    float a=0;
    for(int e=0;e<8;e++) a += qv[e]*s2f(k0[e]) + qv[8+e]*s2f(k1[e]);
    a*=0.25f; sc[j]=a; mx=fmaxf(mx,a);
  }
  float se=0;
  for(int j=0;j<8;j++){ sc[j]=expf(sc[j]-mx); se+=sc[j]; }
  float inv=1.f/se;
  float o[16];
  for(int d=0;d<16;d++) o[d]=0.f;
  for(int j=0;j<8;j++){
    short8 v0=*(const short8*)&base[j*392+256];
    short8 v1=*(const short8*)&base[j*392+264];
    float p=sc[j];
    for(int e=0;e<8;e++){ o[e]=fmaf(p,s2f(v0[e]),o[e]); o[8+e]=fmaf(p,s2f(v1[e]),o[8+e]); }
  }
  short8 o0,o1;
  for(int e=0;e<8;e++){ o0[e]=f2s(o[e]*inv); o1[e]=f2s(o[8+e]*inv); }
  __syncthreads();   // all Qt reads done; U reusable
  // att tile into U[0,4352)
  {
    int r = tok*8+q;
    *(short8*)&U[r*136 + h*16]     = o0;
    *(short8*)&U[r*136 + h*16 + 8] = o1;
  }
  // ---- phase 5: o-proj (A=att in U, Wo in U+4352), x1 = . + bo + h0r
  short* Wl = U + 4352;
  for(int a=0;a<2;a++) for(int b=0;b<2;b++) accA[a][b]=(f32x4){0.f,0.f,0.f,0.f};
  for(int kc2=0;kc2<4;++kc2){
    __syncthreads();
    for(int it=0; it<2; ++it){
      int li=it*256+tid; int row=li>>2, c=li&3;
      *(short8*)&Wl[row*40+c*8] = *(const short8*)(Bto + (size_t)row*128 + kc2*32 + c*8);
    }
    __syncthreads();
    int ka=kc2*32;
    short8 af[2], bfv[2];
    af[0]=*(const short8*)&U[m16*136 + ka + quad*8];
    af[1]=*(const short8*)&U[(16+m16)*136 + ka + quad*8];
    for(int in=0;in<2;in++) bfv[in]=*(const short8*)&Wl[(wns+in*16+m16)*40 + quad*8];
    for(int im=0;im<2;im++) for(int in=0;in<2;in++)
      accA[im][in]=__builtin_amdgcn_mfma_f32_16x16x32_bf16(af[im],bfv[in],accA[im][in],0,0,0);
  }
  for(int in=0;in<2;in++){
    int col=wns+in*16+m16;
    float bv=bo[col];
    for(int im=0;im<2;im++)
      for(int r=0;r<4;r++){
        int grow=bm+im*16+quad*4+r;
        float v=accA[im][in][r]+bv + h0r[im][in][r];
        X1[(size_t)grow*128+col]=f2s(v);
      }
  }
}

// ============================= fused nf: LN -> f1 (lrelu, LDS) -> f2 (+resid, mean8) -> H2 ====
__global__ __launch_bounds__(256) void nf_f1f2(
  const short* __restrict__ X1, const short* __restrict__ Bt1, const float* __restrict__ b1,
  const short* __restrict__ Bt2, const float* __restrict__ b2,
  short* __restrict__ H2)
{
  __shared__ short LB[8448 + 10240];   // [Al(4352)|F1(8448)] U Bl(10240)
  short* Al = LB;
  short* F1 = LB;
  short* Bl = LB + 8448;
  const int tid=threadIdx.x;
  const int bm=blockIdx.x*32;
  for(int it=0; it<2; ++it){
    int li=it*256+tid; int row=li>>4, kc=li&15;
    short8 v = *(const short8*)(X1 + (size_t)(bm+row)*128 + kc*8);
    float f[8]; float ls=0.f,lq=0.f;
    for(int e=0;e<8;e++){ f[e]=s2f(v[e]); ls+=f[e]; lq+=f[e]*f[e]; }
    for(int off=8;off;off>>=1){ ls+=__shfl_xor(ls,off,16); lq+=__shfl_xor(lq,off,16); }
    float mu=ls*(1.f/128.f);
    float var=lq*(1.f/128.f)-mu*mu;
    float rs=rsqrtf(var+1e-5f);
    for(int e=0;e<8;e++) v[e]=f2s((f[e]-mu)*rs);
    *(short8*)&Al[row*136+kc*8]=v;
  }
  const int lane=tid&63, wave=tid>>6;
  const int quad=lane>>4, m16=lane&15;
  // ---- f1: N=256, wave strip 64 ----
  {
    const int wn=wave*64;
    f32x4 acc[2][4];
    for(int a=0;a<2;a++) for(int b=0;b<4;b++) acc[a][b]=(f32x4){0.f,0.f,0.f,0.f};
    for(int kc2=0;kc2<4;++kc2){
      __syncthreads();
      for(int it=0; it<4; ++it){
        int li=it*256+tid; int row=li>>2, c=li&3;
        *(short8*)&Bl[row*40+c*8] = *(const short8*)(Bt1 + (size_t)row*128 + kc2*32 + c*8);
      }
      __syncthreads();
      int ka=kc2*32;
      short8 af[2], bfv[4];
      af[0]=*(const short8*)&Al[m16*136 + ka + quad*8];
      af[1]=*(const short8*)&Al[(16+m16)*136 + ka + quad*8];
      for(int in=0;in<4;in++) bfv[in]=*(const short8*)&Bl[(wn+in*16+m16)*40 + quad*8];
      for(int im=0;im<2;im++)
        for(int in=0;in<4;in++)
          acc[im][in]=__builtin_amdgcn_mfma_f32_16x16x32_bf16(af[im],bfv[in],acc[im][in],0,0,0);
    }
    __syncthreads();   // all Al reads done before F1 overwrites it
    for(int in=0;in<4;in++){
      int col=wn+in*16+m16;
      float bv=b1[col];
      for(int im=0;im<2;im++)
        for(int r=0;r<4;r++){
          float v=acc[im][in][r]+bv;
          v = v>=0.f? v : 0.01f*v;
          F1[(im*16+quad*4+r)*264+col]=f2s(v);
        }
    }
  }
  __syncthreads();
  // ---- f2: K=256 from F1, N=128, wave strip 32, +resid, mean8 -> H2 ----
  {
    const int wn=wave*32;
    f32x4 acc[2][2];
    for(int a=0;a<2;a++) for(int b=0;b<2;b++) acc[a][b]=(f32x4){0.f,0.f,0.f,0.f};
    for(int kc2=0;kc2<8;++kc2){
      __syncthreads();
      for(int it=0; it<2; ++it){
        int li=it*256+tid; int row=li>>2, c=li&3;
        *(short8*)&Bl[row*40+c*8] = *(const short8*)(Bt2 + (size_t)row*256 + kc2*32 + c*8);
      }
      __syncthreads();
      int ka=kc2*32;
      short8 af[2], bfv[2];
      af[0]=*(const short8*)&F1[m16*264 + ka + quad*8];
      af[1]=*(const short8*)&F1[(16+m16)*264 + ka + quad*8];
      for(int in=0;in<2;in++) bfv[in]=*(const short8*)&Bl[(wn+in*16+m16)*40 + quad*8];
      for(int im=0;im<2;im++)
        for(int in=0;in<2;in++)
          acc[im][in]=__builtin_amdgcn_mfma_f32_16x16x32_bf16(af[im],bfv[in],acc[im][in],0,0,0);
    }
    for(int in=0;in<2;in++){
      int col=wn+in*16+m16;
      float bv=b2[col];
      for(int im=0;im<2;im++){
        float s4=0.f;
        for(int r=0;r<4;r++){
          int grow=bm+im*16+quad*4+r;
          float v=acc[im][in][r]+bv + s2f(X1[(size_t)grow*128+col]);
          s4+=v;
        }
        float stok = s4 + __shfl_xor(s4,16,64);
        if((quad&1)==0){
          int tok=((bm+im*16)>>3)+(quad>>1);
          H2[(size_t)tok*128+col]=f2s(stok*0.125f);
        }
      }
    }
  }
}

// ============================= rt attention: 2-way key split in-block =============================
__global__ __launch_bounds__(256) void rt_attn(const short* __restrict__ qkvb, short* __restrict__ attout){
  int b=blockIdx.x; int i=b&255, h0=(b>>8)*4; int tid=threadIdx.x;
  __shared__ float kh[96][64], vh[96][64];   // 49152 B
  for(int idx=tid; idx<1536; idx+=256){
    int kv = idx>=768; int l = idx - kv*768;
    int j = l>>3, c = l&7;
    size_t base = ((size_t)(i*96+j))*384 + h0*16 + (kv?256:128) + c*8;
    short8 x = *(const short8*)(qkvb+base);
    float* dst = kv? &vh[j][c*8] : &kh[j][c*8];
    for(int e=0;e<8;e++) dst[e]=s2f(x[e]);
  }
  __syncthreads();
  int jh=tid>>7, t2=tid&127;
  int hh=t2>>5, lq=t2&31, h=h0+hh, r0=lq*3;
  float q[3][16];
  for(int rr=0;rr<3;rr++){
    size_t qb=((size_t)(i*96+r0+rr))*384 + h*16;
    short8 a=*(const short8*)(qkvb+qb), bq=*(const short8*)(qkvb+qb+8);
    for(int e=0;e<8;e++){ q[rr][e]=s2f(a[e]); q[rr][8+e]=s2f(bq[e]); }
  }
  float acc[3][16]; float se[3]={0.f,0.f,0.f};
  for(int rr=0;rr<3;rr++) for(int d=0;d<16;d++) acc[rr][d]=0.f;
  const float* kb=&kh[jh*48][hh*16];
  const float* vb=&vh[jh*48][hh*16];
  for(int j=0;j<48;j++){
    const float* kj = kb + j*64;
    float s0=0.f,s1=0.f,s2=0.f;
    for(int d=0;d<16;d++){ float kv_=kj[d];
      s0=fmaf(q[0][d],kv_,s0); s1=fmaf(q[1][d],kv_,s1); s2=fmaf(q[2][d],kv_,s2); }
    float p0=expf(s0*0.25f), p1=expf(s1*0.25f), p2=expf(s2*0.25f);
    se[0]+=p0; se[1]+=p1; se[2]+=p2;
    const float* vj = vb + j*64;
    for(int d=0;d<16;d++){ float vv=vj[d];
      acc[0][d]=fmaf(p0,vv,acc[0][d]); acc[1][d]=fmaf(p1,vv,acc[1][d]); acc[2][d]=fmaf(p2,vv,acc[2][d]); }
  }
  __syncthreads();
  float* pacc=(float*)kh;
  float* pse =(float*)vh;
  if(jh==1){
    for(int rr=0;rr<3;rr++){
      for(int d=0;d<16;d++) pacc[(t2*3+rr)*16+d]=acc[rr][d];
      pse[t2*3+rr]=se[rr];
    }
  }
  __syncthreads();
  if(jh==0){
    for(int rr=0;rr<3;rr++){
      float sv = se[rr] + pse[t2*3+rr];
      float inv = 1.f/sv;
      short8 o0,o1;
      for(int e=0;e<8;e++){
        float a0=acc[rr][e]   + pacc[(t2*3+rr)*16+e];
        float a1=acc[rr][8+e] + pacc[(t2*3+rr)*16+8+e];
        o0[e]=f2s(a0*inv); o1[e]=f2s(a1*inv);
      }
      size_t ob=((size_t)(i*96+r0+rr))*128 + h*16;
      *(short8*)(attout+ob)=o0;
      *(short8*)(attout+ob+8)=o1;
    }
  }
}

// ============================= radiance head =============================
__global__ __launch_bounds__(256) void k_rad(
  const short* __restrict__ h3, const float* __restrict__ fW, const float* __restrict__ fb,
  const float* __restrict__ wsf, float* __restrict__ out)
{
  int t=blockIdx.x*256+threadIdx.x;
  if(t>=NT) return;
  int i=t/S;
  float a0=fb[0], a1=fb[1], a2=fb[2];
  for(int c=0;c<C;c++){
    float hv=s2f(h3[(size_t)t*C+c]);
    a0=fmaf(hv,fW[c*3+0],a0);
    a1=fmaf(hv,fW[c*3+1],a1);
    a2=fmaf(hv,fW[c*3+2],a2);
  }
  float m=wsf[OFF_M+i];
  float r0=1.f/(1.f+expf(-a0)), r1=1.f/(1.f+expf(-a1)), r2=1.f/(1.f+expf(-a2));
  size_t ob=3*(size_t)NT+(size_t)t*3;
  out[ob+0]=m!=0.f?r0:0.f;
  out[ob+1]=m!=0.f?r1:0.f;
  out[ob+2]=m!=0.f?r2:0.f;
}

extern "C" void kernel_launch(void* const* d_in, const int* in_sizes, int n_in,
                              void* d_out, int out_size, void* d_ws, size_t ws_size,
                              hipStream_t stream) {
  (void)in_sizes; (void)n_in; (void)out_size;
  const float* rays_o =(const float*)d_in[0];
  const float* rays_d =(const float*)d_in[1];
  const float* pose   =(const float*)d_in[2];
  const float* dimv   =(const float*)d_in[3];
  const float* voxel  =(const float*)d_in[4];
  const float* fvol   =(const float*)d_in[5];
  const float* fvhr   =(const float*)d_in[6];
  const float* u_p    =(const float*)d_in[7];
  const float* u_cat  =(const float*)d_in[8];
  const float* u_lam  =(const float*)d_in[9];
  const float* dW1    =(const float*)d_in[10];
  const float* db1    =(const float*)d_in[11];
  const float* dW2    =(const float*)d_in[12];
  const float* db2    =(const float*)d_in[13];
  const float* rW0    =(const float*)d_in[14];
  const float* rb0    =(const float*)d_in[15];
  const float* nf_qkv =(const float*)d_in[16];
  const float* nf_qkvb=(const float*)d_in[17];
  const float* nf_o   =(const float*)d_in[18];
  const float* nf_ob  =(const float*)d_in[19];
  const float* nf_f1  =(const float*)d_in[20];
  const float* nf_f1b =(const float*)d_in[21];
  const float* nf_f2  =(const float*)d_in[22];
  const float* nf_f2b =(const float*)d_in[23];
  const float* rt_qkv =(const float*)d_in[24];
  const float* rt_qkvb=(const float*)d_in[25];
  const float* rt_o   =(const float*)d_in[26];
  const float* rt_ob  =(const float*)d_in[27];
  const float* rt_f1  =(const float*)d_in[28];
  const float* rt_f1b =(const float*)d_in[29];
  const float* rt_f2  =(const float*)d_in[30];
  const float* rt_f2b =(const float*)d_in[31];
  const float* fW     =(const float*)d_in[32];
  const float* fb     =(const float*)d_in[33];

  float* wsf=(float*)d_ws;
  short* wsb=(short*)((char*)d_ws + F32_CNT*4);
  float* out=(float*)d_out;

  // Chunking: smallest nch that fits ws_size (nch=1 measured fastest overall).
  int nch=8;
  for(int c=1;c<=8;c<<=1){
    size_t mc_=(size_t)MTOT/c;
    size_t region=mc_*640ULL; if(region<RT_TOT) region=RT_TOT;
    size_t need=F32_CNT*4 + 2ULL*(CHB + region);
    if(need <= ws_size){ nch=c; break; }
  }
  const size_t mc = (size_t)MTOT/nch;
  const int Tc = (int)(mc/8);

  short* WT  = wsb;
  short* H2  = wsb + H2OFF;
  short* arena = wsb + CHB;
  // nf chunk overlays: x1[128,256) x2[512,576)
  short* o_x1 = arena + (size_t)128*mc;
  short* o_x2 = arena + (size_t)512*mc;
  // rt overlays: qkv[0,384) att/h3[384,512) x[0,128) f1[128,384)
  short* r_qkv= arena;
  short* r_att= arena + (size_t)384*NT;
  short* r_x  = arena;
  short* r_f1 = arena + (size_t)128*NT;
  short* r_h3 = arena + (size_t)384*NT;

  k0_setup<<<NRAY/64,64,0,stream>>>(rays_o,rays_d,pose,dimv,wsf);
  k1_sample<<<NRAY,128,0,stream>>>(rays_o,rays_d,dimv,voxel,fvol,u_p,u_cat,u_lam,wsf);
  k2_sigma<<<NT,128,0,stream>>>(dW1,db1,dW2,db2,wsf,out);
  k_wprep<<<(int)((WT_TOT+255)/256),256,0,stream>>>(rW0,nf_qkv,nf_o,nf_f1,nf_f2,rt_qkv,rt_o,rt_f1,rt_f2,WT);

  const int mt32=(int)(mc/32);
  for(int ch=0; ch<nch; ++ch){
    int tok0 = ch*Tc;
    k_build<<<Tc/4,256,0,stream>>>(fvhr, wsf, o_x2, tok0);
    nf_front<<<mt32,256,0,stream>>>(o_x2, WT+WT_W0, rb0, WT+WT_NQKV, nf_qkvb,
                                    WT+WT_NO, nf_ob, o_x1);
    nf_f1f2<<<mt32,256,0,stream>>>(o_x1, WT+WT_NF1, nf_f1b, WT+WT_NF2, nf_f2b,
                                   H2+(size_t)tok0*128);
  }

  gemm_ln<128,true ,false,false><<<dim3(NT/128,3),256,0,stream>>>(H2,   WT+WT_RQKV,rt_qkvb, nullptr, r_qkv,384);
  rt_attn<<<NRAY*2,256,0,stream>>>(r_qkv, r_att);
  gemm_ln<128,false,false,true ><<<dim3(NT/128,1),256,0,stream>>>(r_att,WT+WT_RO,  rt_ob,   H2,      r_x,  128);
  gemm_ln<128,true ,true ,false><<<dim3(NT/128,2),256,0,stream>>>(r_x,  WT+WT_RF1, rt_f1b,  nullptr, r_f1, 256);
  gemm_ln<256,false,false,true ><<<dim3(NT/128,1),256,0,stream>>>(r_f1, WT+WT_RF2, rt_f2b,  r_x,     r_h3, 128);
  k_rad<<<NT/256,256,0,stream>>>(r_h3, fW, fb, wsf, out);
}

// Round 17
// 464.267 us; speedup vs baseline: 1.0600x; 1.0600x over previous
//
#include <hip/hip_runtime.h>
#include <hip/hip_bf16.h>
#include <cmath>

// Inputs/outputs float32. Geometry/sampling fp32 (k0/k1/k2). nf + rt chains as
// bf16 MFMA GEMMs (fp32 accum), LN fused into A-staging. FINAL config
// (round 13, best measured 466 us; r15 repro 470):
//  - nf_qkv_attn_o fuses LN+qkv GEMM+attention+o-proj(+h0 resid) per 32-row
//    tile (att tile reuses the dead Qt LDS region). 39.4 KB LDS, 4 blocks/CU.
//  - nf_f1f2 overlays Al (dead after f1 GEMM) with F1 -> 37.4 KB, 4 blocks/CU.
//  - Wider fusion regresses (r14 full-chain: VGPR 128/3 blk; r16 front-fusion:
//    VGPR 116/21% occ): carrying epilogue state across the attention phase
//    costs an occupancy step worth more than the saved launch+traffic.

using bf16 = __hip_bfloat16;
#define DEV __device__ __forceinline__

typedef __attribute__((ext_vector_type(8))) short short8;
typedef __attribute__((ext_vector_type(4))) float f32x4;

DEV float s2f(short s){ unsigned u=((unsigned)(unsigned short)s)<<16; float f; __builtin_memcpy(&f,&u,4); return f; }
DEV short f2s(float f){ bf16 h=__float2bfloat16(f); short r; __builtin_memcpy(&r,&h,2); return r; }

constexpr int NRAY=256, SP=64, SI=32, S=96, KHR=8, CIN=32, C=128, NH=8, DH=16;
constexpr int NT = NRAY*S;           // 24576 tokens
constexpr int MTOT = NT*KHR;         // 196608 rows in the nf chain

// ---- fp32 ws region (element offsets) ----
constexpr size_t OFF_RI=0, OFF_TR=9, OFF_M=16, OFF_TN=272, OFF_TF=528, OFF_RDO=784,
  OFF_TS=1552, OFF_OCCS=26128, OFF_OCCT=50704, OFF_CRD=75280, OFF_XS=149008, F32_CNT=935440;

// ---- bf16 ws region (element offsets from bf16 base) ----
constexpr size_t WT_W0=0, WT_NQKV=8192, WT_NO=57344, WT_NF1=73728, WT_NF2=106496,
  WT_RQKV=139264, WT_RO=188416, WT_RF1=204800, WT_RF2=237568, WT_TOT=270336;
constexpr size_t H2OFF=WT_TOT;                 // h2: NT*128
constexpr size_t CHB=H2OFF+(size_t)NT*128;     // chunk / rt arena base
constexpr size_t RT_TOT=(size_t)NT*512;        // compacted rt arena

struct Corn { int off[8]; float wz, wy, wx; };

DEV void make_corners(float cz, float cy, float cx, Corn& Cn){
  cz=fminf(fmaxf(cz,0.f),31.f); cy=fminf(fmaxf(cy,0.f),31.f); cx=fminf(fmaxf(cx,0.f),31.f);
  int z0=(int)cz, y0=(int)cy, x0=(int)cx;
  int z1=(z0+1<31)?z0+1:31, y1=(y0+1<31)?y0+1:31, x1=(x0+1<31)?x0+1:31;
  Cn.wz=cz-(float)z0; Cn.wy=cy-(float)y0; Cn.wx=cx-(float)x0;
  int zy00=z0*1024+y0*32, zy01=z0*1024+y1*32, zy10=z1*1024+y0*32, zy11=z1*1024+y1*32;
  Cn.off[0]=zy00+x0; Cn.off[1]=zy00+x1;
  Cn.off[2]=zy01+x0; Cn.off[3]=zy01+x1;
  Cn.off[4]=zy10+x0; Cn.off[5]=zy10+x1;
  Cn.off[6]=zy11+x0; Cn.off[7]=zy11+x1;
}

DEV float interp1(const float* __restrict__ vol, const Corn& Cn){
  float v000=vol[Cn.off[0]], v001=vol[Cn.off[1]];
  float v010=vol[Cn.off[2]], v011=vol[Cn.off[3]];
  float v100=vol[Cn.off[4]], v101=vol[Cn.off[5]];
  float v110=vol[Cn.off[6]], v111=vol[Cn.off[7]];
  float wx=Cn.wx, wy=Cn.wy, wz=Cn.wz;
  float c00=v000*(1.f-wx)+v001*wx, c01=v010*(1.f-wx)+v011*wx;
  float c10=v100*(1.f-wx)+v101*wx, c11=v110*(1.f-wx)+v111*wx;
  return (c00*(1.f-wy)+c01*wy)*(1.f-wz) + (c10*(1.f-wy)+c11*wy)*wz;
}

DEV float ray_box(const float* Ri, const float* tr, const float* o3, const float* d3, const float* half){
  float tlo=-INFINITY, thi=INFINITY;
  for(int j=0;j<3;j++){
    float oo=Ri[j*3+0]*o3[0]+Ri[j*3+1]*o3[1]+Ri[j*3+2]*o3[2]+tr[j];
    float dd=Ri[j*3+0]*d3[0]+Ri[j*3+1]*d3[1]+Ri[j*3+2]*d3[2];
    if (fabsf(dd)<1e-9f) dd=1e-9f;
    float inv=1.f/dd;
    float t0=(-half[j]-oo)*inv, t1=(half[j]-oo)*inv;
    tlo=fmaxf(tlo,fminf(t0,t1)); thi=fminf(thi,fmaxf(t0,t1));
  }
  bool valid = thi >= fmaxf(tlo,0.f);
  return valid ? tlo : INFINITY;
}

// ============================= k0: pose inverse + ray-box =============================
__global__ __launch_bounds__(64) void k0_setup(
  const float* __restrict__ rays_o, const float* __restrict__ rays_d,
  const float* __restrict__ pose, const float* __restrict__ dimv,
  float* __restrict__ wsf)
{
  __shared__ float Ri[9], tr[3];
  int tid=threadIdx.x; int ray=blockIdx.x*64+tid;
  if(tid==0){
    float P[16];
    for(int j=0;j<16;j++) P[j]=pose[j];
    float a00=P[0],a01=P[1],a02=P[2],a10=P[4],a11=P[5],a12=P[6],a20=P[8],a21=P[9],a22=P[10];
    float c00=a11*a22-a12*a21, c01=a12*a20-a10*a22, c02=a10*a21-a11*a20;
    float det=a00*c00+a01*c01+a02*c02;
    float id=1.f/det;
    Ri[0]=c00*id; Ri[1]=(a02*a21-a01*a22)*id; Ri[2]=(a01*a12-a02*a11)*id;
    Ri[3]=c01*id; Ri[4]=(a00*a22-a02*a20)*id; Ri[5]=(a02*a10-a00*a12)*id;
    Ri[6]=c02*id; Ri[7]=(a01*a20-a00*a21)*id; Ri[8]=(a00*a11-a01*a10)*id;
    float t0=P[3],t1=P[7],t2=P[11];
    tr[0]=-(Ri[0]*t0+Ri[1]*t1+Ri[2]*t2);
    tr[1]=-(Ri[3]*t0+Ri[4]*t1+Ri[5]*t2);
    tr[2]=-(Ri[6]*t0+Ri[7]*t1+Ri[8]*t2);
    if(blockIdx.x==0){
      for(int j=0;j<9;j++) wsf[OFF_RI+j]=Ri[j];
      for(int j=0;j<3;j++) wsf[OFF_TR+j]=tr[j];
    }
  }
  __syncthreads();
  float o3[3],d3[3],dim[3],half[3];
  for(int j=0;j<3;j++){ o3[j]=rays_o[ray*3+j]; d3[j]=rays_d[ray*3+j];
                        dim[j]=dimv[j]; half[j]=0.5f*dim[j]; }
  float tnear=ray_box(Ri,tr,o3,d3,half);
  float tmax=tnear+10.f*(fabsf(dim[0])+fabsf(dim[1])+fabsf(dim[2]));
  float pm[3]={o3[0]+tmax*d3[0], o3[1]+tmax*d3[1], o3[2]+tmax*d3[2]};
  float nd[3]={-d3[0],-d3[1],-d3[2]};
  float tfar=tmax-ray_box(Ri,tr,pm,nd,half);
  bool mm = isfinite(tnear)&&isfinite(tfar)&&(tfar>tnear);
  wsf[OFF_M+ray]=mm?1.f:0.f;
  wsf[OFF_TN+ray]=mm?tnear:0.f;
  wsf[OFF_TF+ray]=mm?tfar:1.f;
  for(int j=0;j<3;j++)
    wsf[OFF_RDO+(size_t)ray*3+j]=Ri[j*3+0]*d3[0]+Ri[j*3+1]*d3[1]+Ri[j*3+2]*d3[2];
}

// ============================= k1: sampling + interp + stable sort =============================
__global__ __launch_bounds__(128) void k1_sample(
  const float* __restrict__ rays_o, const float* __restrict__ rays_d, const float* __restrict__ dimv,
  const float* __restrict__ voxel, const float* __restrict__ fvol,
  const float* __restrict__ u_p, const float* __restrict__ u_cat, const float* __restrict__ u_lam,
  float* __restrict__ wsf)
{
  int i=blockIdx.x, tid=threadIdx.x;
  __shared__ float Ri[9], tr[3], dim[3], o3[3], d3[3];
  __shared__ float t_all[S], occ_all[S], crd_sh[S][3];
  __shared__ int   coff[S][8];
  __shared__ float cww[S][3];
  __shared__ float cdf[SP];
  __shared__ float totv;
  __shared__ int   rnk[S];
  if(tid<9) Ri[tid]=wsf[OFF_RI+tid];
  if(tid<3){ tr[tid]=wsf[OFF_TR+tid]; dim[tid]=dimv[tid];
             o3[tid]=rays_o[i*3+tid]; d3[tid]=rays_d[i*3+tid]; }
  __syncthreads();
  float tn=wsf[OFF_TN+i], tf=wsf[OFF_TF+i];

  auto do_sample=[&](int s, float t){
    float px=o3[0]+t*d3[0], py=o3[1]+t*d3[1], pz=o3[2]+t*d3[2];
    float q0=Ri[0]*px+Ri[1]*py+Ri[2]*pz+tr[0];
    float q1=Ri[3]*px+Ri[4]*py+Ri[5]*pz+tr[1];
    float q2=Ri[6]*px+Ri[7]*py+Ri[8]*pz+tr[2];
    float cz=(0.5f+q2/dim[2])*31.f;
    float cy=(0.5f+q1/dim[1])*31.f;
    float cx=(0.5f+q0/dim[0])*31.f;
    crd_sh[s][0]=cz; crd_sh[s][1]=cy; crd_sh[s][2]=cx;
    Corn Cn; make_corners(cz,cy,cx,Cn);
    for(int q=0;q<8;q++) coff[s][q]=Cn.off[q];
    cww[s][0]=Cn.wz; cww[s][1]=Cn.wy; cww[s][2]=Cn.wx;
    occ_all[s]=interp1(voxel,Cn);
    t_all[s]=t;
  };

  if(tid<SP){
    float u=u_p[i*SP+tid];
    float t=tn+(tf-tn)*((float)tid+u)*(1.f/64.f);
    do_sample(tid,t);
  }
  __syncthreads();
  if(tid==0){
    float c=0;
    for(int j=0;j<SP-1;j++){ float pr=occ_all[j]+occ_all[j+1]; pr=fmaxf(pr,1e-12f); c+=pr; cdf[j]=c; }
    totv=c;
  }
  __syncthreads();
  if(tid<SP-1) cdf[tid]=cdf[tid]/totv;
  __syncthreads();
  if(tid<SI){
    float u=u_cat[i*SI+tid];
    int cnt=0;
    for(int j=0;j<SP-1;j++) cnt += (u>=cdf[j])?1:0;
    int ind=(cnt<SP-2)?cnt:(SP-2);
    float lam=u_lam[i*SI+tid];
    float tfine=lam*t_all[ind]+(1.f-lam)*t_all[ind+1];
    do_sample(SP+tid,tfine);
  }
  __syncthreads();
  if(tid<S){  // stable counting-rank sort (== stable argsort)
    float ts=t_all[tid]; int r=0;
    for(int j=0;j<S;j++){ float tj=t_all[j]; r += (tj<ts || (tj==ts && j<tid)) ? 1:0; }
    rnk[tid]=r;
    size_t base=(size_t)i*S+r;
    wsf[OFF_TS+base]=ts;
    wsf[OFF_OCCS+base]=occ_all[tid];
    wsf[OFF_CRD+base*3+0]=crd_sh[tid][0];
    wsf[OFF_CRD+base*3+1]=crd_sh[tid][1];
    wsf[OFF_CRD+base*3+2]=crd_sh[tid][2];
  }
  __syncthreads();
  for(int idx=tid; idx<S*CIN; idx+=128){
    int s=idx>>5, c=idx&31;
    float wz=cww[s][0], wy=cww[s][1], wx=cww[s][2];
    const float* vc=fvol+(size_t)c*32768;
    float v000=vc[coff[s][0]], v001=vc[coff[s][1]];
    float v010=vc[coff[s][2]], v011=vc[coff[s][3]];
    float v100=vc[coff[s][4]], v101=vc[coff[s][5]];
    float v110=vc[coff[s][6]], v111=vc[coff[s][7]];
    float c00=v000*(1.f-wx)+v001*wx, c01=v010*(1.f-wx)+v011*wx;
    float c10=v100*(1.f-wx)+v101*wx, c11=v110*(1.f-wx)+v111*wx;
    float val=(c00*(1.f-wy)+c01*wy)*(1.f-wz)+(c10*(1.f-wy)+c11*wy)*wz;
    wsf[OFF_XS+((size_t)i*S+rnk[s])*CIN+c]=val;
  }
}

// ============================= k2: sigma MLP, alpha, outputs 0..2 =============================
__global__ __launch_bounds__(128) void k2_sigma(
  const float* __restrict__ dW1, const float* __restrict__ db1,
  const float* __restrict__ dW2, const float* __restrict__ db2,
  float* __restrict__ wsf, float* __restrict__ out)
{
  int t=blockIdx.x, tid=threadIdx.x, i=t/S;
  __shared__ float xx[33];
  __shared__ float part[2];
  if(tid<32) xx[tid]=wsf[OFF_XS+(size_t)t*32+tid];
  if(tid==32) xx[32]=wsf[OFF_OCCS+t];
  __syncthreads();
  float acc=db1[tid];
  for(int k=0;k<33;k++) acc=fmaf(xx[k], dW1[k*C+tid], acc);
  acc = acc>=0.f?acc:0.01f*acc;
  float g = acc*dW2[tid];
  for(int off=32;off;off>>=1) g+=__shfl_down(g,off,64);
  if((tid&63)==0) part[tid>>6]=g;
  __syncthreads();
  if(tid==0){
    float z=part[0]+part[1]+db2[0];
    float sg=1.f/(1.f+expf(-z));
    float occ=xx[32];
    float occt=occ<0.7f?0.f:occ;
    float alpha=occt*sg;
    float m=wsf[OFF_M+i];
    float ts=wsf[OFF_TS+t];
    out[t]      =m!=0.f?ts:0.f;
    out[NT+t]   =m!=0.f?alpha:0.f;
    out[2*NT+t] =m!=0.f?occt:0.f;
    wsf[OFF_OCCT+t]=occt;
  }
}

// ============================= weight prep: fp32 KxN -> bf16 N x Kpad (B^T) =============================
__global__ __launch_bounds__(256) void k_wprep(
  const float* __restrict__ w0, const float* __restrict__ nqkv, const float* __restrict__ no_,
  const float* __restrict__ nf1, const float* __restrict__ nf2,
  const float* __restrict__ rqkv, const float* __restrict__ ro_,
  const float* __restrict__ rf1, const float* __restrict__ rf2,
  short* __restrict__ WT)
{
  int gid = blockIdx.x*256+threadIdx.x;
  if(gid>=(int)WT_TOT) return;
  const float* src; int K,N,Kp; int base;
  if(gid<8192){src=w0;K=42;N=128;Kp=64;base=0;}
  else if(gid<57344){src=nqkv;K=128;N=384;Kp=128;base=8192;}
  else if(gid<73728){src=no_;K=128;N=128;Kp=128;base=57344;}
  else if(gid<106496){src=nf1;K=128;N=256;Kp=128;base=73728;}
  else if(gid<139264){src=nf2;K=256;N=128;Kp=256;base=106496;}
  else if(gid<188416){src=rqkv;K=128;N=384;Kp=128;base=139264;}
  else if(gid<204800){src=ro_;K=128;N=128;Kp=128;base=188416;}
  else if(gid<237568){src=rf1;K=128;N=256;Kp=128;base=204800;}
  else {src=rf2;K=256;N=128;Kp=256;base=237568;}
  int local=gid-base; int n=local/Kp, k=local%Kp;
  WT[gid] = (k<K)? f2s(src[(size_t)k*N+n]) : (short)0;
}

// ============================= xx2 builder: 4 tokens/block =============================
__global__ __launch_bounds__(256) void k_build(
  const float* __restrict__ fvhr, const float* __restrict__ wsf,
  short* __restrict__ X2, int tok0)
{
  int tid=threadIdx.x; int sub=tid>>6, stid=tid&63;
  int tloc=blockIdx.x*4+sub;
  int t=tok0+tloc, i=t/S;
  __shared__ float hr[4][KHR][6];
  __shared__ float xf[4][32];
  __shared__ float RiS[9];
  __shared__ float geo[4][4];
  __shared__ float crd[4][3];
  if(tid<9) RiS[tid]=wsf[OFF_RI+tid];
  if(stid>=16&&stid<19) crd[sub][stid-16]=wsf[OFF_CRD+(size_t)t*3+(stid-16)];
  if(stid>=32) xf[sub][stid-32]=wsf[OFF_XS+(size_t)t*32+(stid-32)];
  if(stid==9) geo[sub][0]=wsf[OFF_OCCT+t];
  if(stid>=12&&stid<15) geo[sub][1+(stid-12)]=wsf[OFF_RDO+(size_t)i*3+(stid-12)];
  __syncthreads();
  if(stid<48){
    int k=stid/6, ch=stid%6;
    Corn Cn; make_corners(crd[sub][0],crd[sub][1],crd[sub][2],Cn);
    hr[sub][k][ch]=interp1(fvhr+(size_t)(k*6+ch)*32768, Cn);
  }
  __syncthreads();
  for(int idx=stid; idx<512; idx+=64){
    int k=idx>>6, j=idx&63; float v;
    if(j<32) v=xf[sub][j];
    else if(j<35) v=hr[sub][k][j-32];
    else if(j<38){int r=j-35; v=hr[sub][k][3]*RiS[r*3+0]+hr[sub][k][4]*RiS[r*3+1]+hr[sub][k][5]*RiS[r*3+2];}
    else if(j<41) v=geo[sub][1+(j-38)];
    else if(j==41) v=geo[sub][0];
    else v=0.f;
    X2[(size_t)(tloc*8+k)*64 + j]=f2s(v);
  }
}

// ============================= MFMA GEMM: C = [LN?](A) @ Bt^T + bias [+lrelu] [+resid] =============================
template<int K, bool LNA, bool ACT, bool RESID>
__global__ __launch_bounds__(256) void gemm_ln(
  const short* __restrict__ A, const short* __restrict__ Bt,
  const float* __restrict__ bias, const short* __restrict__ Rres,
  short* __restrict__ Cg, int N)
{
  static_assert(!LNA || K==128, "LNA requires K==128");
  constexpr int KSA = (K<128)?K:128;
  constexpr int NSA = K/KSA;
  constexpr int LDA = KSA+8;
  constexpr int LDB = 64+8;
  __shared__ short Al[128*LDA];
  __shared__ short Bl[128*LDB];
  const int tid=threadIdx.x;
  const int bm=blockIdx.x*128, bn=blockIdx.y*128;
  const int lane=tid&63, wave=tid>>6;
  const int wm=(wave>>1)*64, wn=(wave&1)*64;
  const int quad=lane>>4, m16=lane&15;
  f32x4 acc[4][4];
  for(int a=0;a<4;a++) for(int b=0;b<4;b++) acc[a][b]=(f32x4){0.f,0.f,0.f,0.f};

  for(int sa=0; sa<NSA; ++sa){
    if(sa>0) __syncthreads();
    constexpr int CH8=KSA/8;
    for(int it=0; it<(128*CH8)/256; ++it){
      int li=it*256+tid; int row=li/CH8, kc=li%CH8;
      short8 v = *(const short8*)(A + (size_t)(bm+row)*K + sa*KSA + kc*8);
      if constexpr(LNA){
        float f[8]; float ls=0.f,lq=0.f;
        for(int e=0;e<8;e++){ f[e]=s2f(v[e]); ls+=f[e]; lq+=f[e]*f[e]; }
        for(int off=8;off;off>>=1){ ls+=__shfl_xor(ls,off,16); lq+=__shfl_xor(lq,off,16); }
        float mu=ls*(1.f/128.f);
        float var=lq*(1.f/128.f)-mu*mu;
        float rs=rsqrtf(var+1e-5f);
        for(int e=0;e<8;e++) v[e]=f2s((f[e]-mu)*rs);
      }
      *(short8*)&Al[row*LDA+kc*8]=v;
    }
    __syncthreads();
    for(int sb=0; sb<KSA/64; ++sb){
      if(sb>0) __syncthreads();
      for(int it=0; it<4; ++it){
        int li=it*256+tid; int row=li>>3, kc=li&7;
        *(short8*)&Bl[row*LDB+kc*8] =
          *(const short8*)(Bt + (size_t)(bn+row)*K + sa*KSA + sb*64 + kc*8);
      }
      __syncthreads();
      for(int kk=0; kk<64; kk+=32){
        int ka = sb*64+kk;
        short8 af[4], bfv[4];
        for(int im=0; im<4; im++)
          af[im] = *(const short8*)&Al[(wm+im*16+m16)*LDA + ka + quad*8];
        for(int in=0; in<4; in++)
          bfv[in] = *(const short8*)&Bl[(wn+in*16+m16)*LDB + kk + quad*8];
        for(int im=0;im<4;im++)
          for(int in=0;in<4;in++)
            acc[im][in] = __builtin_amdgcn_mfma_f32_16x16x32_bf16(af[im], bfv[in], acc[im][in], 0,0,0);
      }
    }
  }
  for(int in=0;in<4;in++){
    int col = bn + wn + in*16 + m16;
    float bv = bias[col];
    for(int im=0;im<4;im++){
      for(int r=0;r<4;r++){
        int grow = bm + wm + im*16 + quad*4 + r;
        float v = acc[im][in][r] + bv;
        if constexpr(ACT) v = v>=0.f? v : 0.01f*v;
        if constexpr(RESID) v += s2f(Rres[(size_t)grow*N + col]);
        Cg[(size_t)grow*N + col] = f2s(v);
      }
    }
  }
}

// ============================= fused nf: LN -> qkv GEMM -> attention -> o-proj(+h0) -> x1 ====
__global__ __launch_bounds__(256) void nf_qkv_attn_o(
  const short* __restrict__ A, const short* __restrict__ Btq,
  const float* __restrict__ bq, const short* __restrict__ Bto,
  const float* __restrict__ bo, short* __restrict__ X1)
{
  __shared__ short Al[32*136];
  __shared__ short U[15360];   // Bl qkv 15360 | Qt 12544 | att 4352 + Wo 5120
  short* Bl = U;
  short* Qt = U;
  const int tid=threadIdx.x;
  const int bm=blockIdx.x*32;
  for(int it=0; it<2; ++it){
    int li=it*256+tid; int row=li>>4, kc=li&15;
    short8 v = *(const short8*)(A + (size_t)(bm+row)*128 + kc*8);
    float f[8]; float ls=0.f,lq=0.f;
    for(int e=0;e<8;e++){ f[e]=s2f(v[e]); ls+=f[e]; lq+=f[e]*f[e]; }
    for(int off=8;off;off>>=1){ ls+=__shfl_xor(ls,off,16); lq+=__shfl_xor(lq,off,16); }
    float mu=ls*(1.f/128.f);
    float var=lq*(1.f/128.f)-mu*mu;
    float rs=rsqrtf(var+1e-5f);
    for(int e=0;e<8;e++) v[e]=f2s((f[e]-mu)*rs);
    *(short8*)&Al[row*136+kc*8]=v;
  }
  const int lane=tid&63, wave=tid>>6;
  const int quad=lane>>4, m16=lane&15;
  const int wn=wave*96;
  f32x4 acc[2][6];
  for(int a=0;a<2;a++) for(int b=0;b<6;b++) acc[a][b]=(f32x4){0.f,0.f,0.f,0.f};
  for(int kc2=0;kc2<4;++kc2){
    __syncthreads();
    for(int it=0; it<6; ++it){
      int li=it*256+tid; int row=li>>2, c=li&3;
      *(short8*)&Bl[row*40+c*8] = *(const short8*)(Btq + (size_t)row*128 + kc2*32 + c*8);
    }
    __syncthreads();
    int ka=kc2*32;
    short8 af[2], bfv[6];
    af[0]=*(const short8*)&Al[m16*136 + ka + quad*8];
    af[1]=*(const short8*)&Al[(16+m16)*136 + ka + quad*8];
    for(int in=0;in<6;in++) bfv[in]=*(const short8*)&Bl[(wn+in*16+m16)*40 + quad*8];
    for(int im=0;im<2;im++)
      for(int in=0;in<6;in++)
        acc[im][in]=__builtin_amdgcn_mfma_f32_16x16x32_bf16(af[im],bfv[in],acc[im][in],0,0,0);
  }
  __syncthreads();   // Bl reads drained before Qt overwrites U
  for(int in=0;in<6;in++){
    int col=wn+in*16+m16;
    float bv=bq[col];
    for(int im=0;im<2;im++)
      for(int r=0;r<4;r++)
        Qt[(im*16+quad*4+r)*392+col]=f2s(acc[im][in][r]+bv);
  }
  __syncthreads();
  int tok=tid>>6, h=(tid>>3)&7, q=tid&7;
  const short* base=&Qt[(tok*8)*392 + h*16];
  short8 q0v=*(const short8*)&base[q*392];
  short8 q1v=*(const short8*)&base[q*392+8];
  float qv[16];
  for(int e=0;e<8;e++){ qv[e]=s2f(q0v[e]); qv[8+e]=s2f(q1v[e]); }
  float sc[8]; float mx=-INFINITY;
  for(int j=0;j<8;j++){
    short8 k0=*(const short8*)&base[j*392+128];
    short8 k1=*(const short8*)&base[j*392+136];
    float a=0;
    for(int e=0;e<8;e++) a += qv[e]*s2f(k0[e]) + qv[8+e]*s2f(k1[e]);
    a*=0.25f; sc[j]=a; mx=fmaxf(mx,a);
  }
  float se=0;
  for(int j=0;j<8;j++){ sc[j]=expf(sc[j]-mx); se+=sc[j]; }
  float inv=1.f/se;
  float o[16];
  for(int d=0;d<16;d++) o[d]=0.f;
  for(int j=0;j<8;j++){
    short8 v0=*(const short8*)&base[j*392+256];
    short8 v1=*(const short8*)&base[j*392+264];
    float p=sc[j];
    for(int e=0;e<8;e++){ o[e]=fmaf(p,s2f(v0[e]),o[e]); o[8+e]=fmaf(p,s2f(v1[e]),o[8+e]); }
  }
  short8 o0,o1;
  for(int e=0;e<8;e++){ o0[e]=f2s(o[e]*inv); o1[e]=f2s(o[8+e]*inv); }
  __syncthreads();   // all Qt reads done; U reusable
  {
    int r = tok*8+q;
    *(short8*)&U[r*136 + h*16]     = o0;
    *(short8*)&U[r*136 + h*16 + 8] = o1;
  }
  short* Wl = U + 4352;
  const int wn2 = wave*32;
  f32x4 acc2[2][2];
  for(int a=0;a<2;a++) for(int b=0;b<2;b++) acc2[a][b]=(f32x4){0.f,0.f,0.f,0.f};
  for(int kc2=0;kc2<4;++kc2){
    __syncthreads();
    for(int it=0; it<2; ++it){
      int li=it*256+tid; int row=li>>2, c=li&3;
      *(short8*)&Wl[row*40+c*8] = *(const short8*)(Bto + (size_t)row*128 + kc2*32 + c*8);
    }
    __syncthreads();
    int ka=kc2*32;
    short8 af[2], bfv[2];
    af[0]=*(const short8*)&U[m16*136 + ka + quad*8];
    af[1]=*(const short8*)&U[(16+m16)*136 + ka + quad*8];
    for(int in=0;in<2;in++) bfv[in]=*(const short8*)&Wl[(wn2+in*16+m16)*40 + quad*8];
    for(int im=0;im<2;im++)
      for(int in=0;in<2;in++)
        acc2[im][in]=__builtin_amdgcn_mfma_f32_16x16x32_bf16(af[im],bfv[in],acc2[im][in],0,0,0);
  }
  for(int in=0;in<2;in++){
    int col=wn2+in*16+m16;
    float bv=bo[col];
    for(int im=0;im<2;im++)
      for(int r=0;r<4;r++){
        int grow=bm+im*16+quad*4+r;
        float v=acc2[im][in][r]+bv + s2f(A[(size_t)grow*128+col]);
        X1[(size_t)grow*128+col]=f2s(v);
      }
  }
}

// ============================= fused nf: LN -> f1 (lrelu, LDS) -> f2 (+resid, mean8) -> H2 ====
__global__ __launch_bounds__(256) void nf_f1f2(
  const short* __restrict__ X1, const short* __restrict__ Bt1, const float* __restrict__ b1,
  const short* __restrict__ Bt2, const float* __restrict__ b2,
  short* __restrict__ H2)
{
  __shared__ short LB[8448 + 10240];   // [Al(4352)|F1(8448)] U Bl(10240)
  short* Al = LB;
  short* F1 = LB;
  short* Bl = LB + 8448;
  const int tid=threadIdx.x;
  const int bm=blockIdx.x*32;
  for(int it=0; it<2; ++it){
    int li=it*256+tid; int row=li>>4, kc=li&15;
    short8 v = *(const short8*)(X1 + (size_t)(bm+row)*128 + kc*8);
    float f[8]; float ls=0.f,lq=0.f;
    for(int e=0;e<8;e++){ f[e]=s2f(v[e]); ls+=f[e]; lq+=f[e]*f[e]; }
    for(int off=8;off;off>>=1){ ls+=__shfl_xor(ls,off,16); lq+=__shfl_xor(lq,off,16); }
    float mu=ls*(1.f/128.f);
    float var=lq*(1.f/128.f)-mu*mu;
    float rs=rsqrtf(var+1e-5f);
    for(int e=0;e<8;e++) v[e]=f2s((f[e]-mu)*rs);
    *(short8*)&Al[row*136+kc*8]=v;
  }
  const int lane=tid&63, wave=tid>>6;
  const int quad=lane>>4, m16=lane&15;
  // ---- f1: N=256, wave strip 64 ----
  {
    const int wn=wave*64;
    f32x4 acc[2][4];
    for(int a=0;a<2;a++) for(int b=0;b<4;b++) acc[a][b]=(f32x4){0.f,0.f,0.f,0.f};
    for(int kc2=0;kc2<4;++kc2){
      __syncthreads();
      for(int it=0; it<4; ++it){
        int li=it*256+tid; int row=li>>2, c=li&3;
        *(short8*)&Bl[row*40+c*8] = *(const short8*)(Bt1 + (size_t)row*128 + kc2*32 + c*8);
      }
      __syncthreads();
      int ka=kc2*32;
      short8 af[2], bfv[4];
      af[0]=*(const short8*)&Al[m16*136 + ka + quad*8];
      af[1]=*(const short8*)&Al[(16+m16)*136 + ka + quad*8];
      for(int in=0;in<4;in++) bfv[in]=*(const short8*)&Bl[(wn+in*16+m16)*40 + quad*8];
      for(int im=0;im<2;im++)
        for(int in=0;in<4;in++)
          acc[im][in]=__builtin_amdgcn_mfma_f32_16x16x32_bf16(af[im],bfv[in],acc[im][in],0,0,0);
    }
    __syncthreads();   // all Al reads done before F1 overwrites it
    for(int in=0;in<4;in++){
      int col=wn+in*16+m16;
      float bv=b1[col];
      for(int im=0;im<2;im++)
        for(int r=0;r<4;r++){
          float v=acc[im][in][r]+bv;
          v = v>=0.f? v : 0.01f*v;
          F1[(im*16+quad*4+r)*264+col]=f2s(v);
        }
    }
  }
  __syncthreads();
  // ---- f2: K=256 from F1, N=128, wave strip 32, +resid, mean8 -> H2 ----
  {
    const int wn=wave*32;
    f32x4 acc[2][2];
    for(int a=0;a<2;a++) for(int b=0;b<2;b++) acc[a][b]=(f32x4){0.f,0.f,0.f,0.f};
    for(int kc2=0;kc2<8;++kc2){
      __syncthreads();
      for(int it=0; it<2; ++it){
        int li=it*256+tid; int row=li>>2, c=li&3;
        *(short8*)&Bl[row*40+c*8] = *(const short8*)(Bt2 + (size_t)row*256 + kc2*32 + c*8);
      }
      __syncthreads();
      int ka=kc2*32;
      short8 af[2], bfv[2];
      af[0]=*(const short8*)&F1[m16*264 + ka + quad*8];
      af[1]=*(const short8*)&F1[(16+m16)*264 + ka + quad*8];
      for(int in=0;in<2;in++) bfv[in]=*(const short8*)&Bl[(wn+in*16+m16)*40 + quad*8];
      for(int im=0;im<2;im++)
        for(int in=0;in<2;in++)
          acc[im][in]=__builtin_amdgcn_mfma_f32_16x16x32_bf16(af[im],bfv[in],acc[im][in],0,0,0);
    }
    for(int in=0;in<2;in++){
      int col=wn+in*16+m16;
      float bv=b2[col];
      for(int im=0;im<2;im++){
        float s4=0.f;
        for(int r=0;r<4;r++){
          int grow=bm+im*16+quad*4+r;
          float v=acc[im][in][r]+bv + s2f(X1[(size_t)grow*128+col]);
          s4+=v;
        }
        float stok = s4 + __shfl_xor(s4,16,64);
        if((quad&1)==0){
          int tok=((bm+im*16)>>3)+(quad>>1);
          H2[(size_t)tok*128+col]=f2s(stok*0.125f);
        }
      }
    }
  }
}

// ============================= rt attention: 2-way key split in-block =============================
__global__ __launch_bounds__(256) void rt_attn(const short* __restrict__ qkvb, short* __restrict__ attout){
  int b=blockIdx.x; int i=b&255, h0=(b>>8)*4; int tid=threadIdx.x;
  __shared__ float kh[96][64], vh[96][64];   // 49152 B
  for(int idx=tid; idx<1536; idx+=256){
    int kv = idx>=768; int l = idx - kv*768;
    int j = l>>3, c = l&7;
    size_t base = ((size_t)(i*96+j))*384 + h0*16 + (kv?256:128) + c*8;
    short8 x = *(const short8*)(qkvb+base);
    float* dst = kv? &vh[j][c*8] : &kh[j][c*8];
    for(int e=0;e<8;e++) dst[e]=s2f(x[e]);
  }
  __syncthreads();
  int jh=tid>>7, t2=tid&127;
  int hh=t2>>5, lq=t2&31, h=h0+hh, r0=lq*3;
  float q[3][16];
  for(int rr=0;rr<3;rr++){
    size_t qb=((size_t)(i*96+r0+rr))*384 + h*16;
    short8 a=*(const short8*)(qkvb+qb), bq=*(const short8*)(qkvb+qb+8);
    for(int e=0;e<8;e++){ q[rr][e]=s2f(a[e]); q[rr][8+e]=s2f(bq[e]); }
  }
  float acc[3][16]; float se[3]={0.f,0.f,0.f};
  for(int rr=0;rr<3;rr++) for(int d=0;d<16;d++) acc[rr][d]=0.f;
  const float* kb=&kh[jh*48][hh*16];
  const float* vb=&vh[jh*48][hh*16];
  for(int j=0;j<48;j++){
    const float* kj = kb + j*64;
    float s0=0.f,s1=0.f,s2=0.f;
    for(int d=0;d<16;d++){ float kv_=kj[d];
      s0=fmaf(q[0][d],kv_,s0); s1=fmaf(q[1][d],kv_,s1); s2=fmaf(q[2][d],kv_,s2); }
    float p0=expf(s0*0.25f), p1=expf(s1*0.25f), p2=expf(s2*0.25f);
    se[0]+=p0; se[1]+=p1; se[2]+=p2;
    const float* vj = vb + j*64;
    for(int d=0;d<16;d++){ float vv=vj[d];
      acc[0][d]=fmaf(p0,vv,acc[0][d]); acc[1][d]=fmaf(p1,vv,acc[1][d]); acc[2][d]=fmaf(p2,vv,acc[2][d]); }
  }
  __syncthreads();
  float* pacc=(float*)kh;
  float* pse =(float*)vh;
  if(jh==1){
    for(int rr=0;rr<3;rr++){
      for(int d=0;d<16;d++) pacc[(t2*3+rr)*16+d]=acc[rr][d];
      pse[t2*3+rr]=se[rr];
    }
  }
  __syncthreads();
  if(jh==0){
    for(int rr=0;rr<3;rr++){
      float sv = se[rr] + pse[t2*3+rr];
      float inv = 1.f/sv;
      short8 o0,o1;
      for(int e=0;e<8;e++){
        float a0=acc[rr][e]   + pacc[(t2*3+rr)*16+e];
        float a1=acc[rr][8+e] + pacc[(t2*3+rr)*16+8+e];
        o0[e]=f2s(a0*inv); o1[e]=f2s(a1*inv);
      }
      size_t ob=((size_t)(i*96+r0+rr))*128 + h*16;
      *(short8*)(attout+ob)=o0;
      *(short8*)(attout+ob+8)=o1;
    }
  }
}

// ============================= radiance head =============================
__global__ __launch_bounds__(256) void k_rad(
  const short* __restrict__ h3, const float* __restrict__ fW, const float* __restrict__ fb,
  const float* __restrict__ wsf, float* __restrict__ out)
{
  int t=blockIdx.x*256+threadIdx.x;
  if(t>=NT) return;
  int i=t/S;
  float a0=fb[0], a1=fb[1], a2=fb[2];
  for(int c=0;c<C;c++){
    float hv=s2f(h3[(size_t)t*C+c]);
    a0=fmaf(hv,fW[c*3+0],a0);
    a1=fmaf(hv,fW[c*3+1],a1);
    a2=fmaf(hv,fW[c*3+2],a2);
  }
  float m=wsf[OFF_M+i];
  float r0=1.f/(1.f+expf(-a0)), r1=1.f/(1.f+expf(-a1)), r2=1.f/(1.f+expf(-a2));
  size_t ob=3*(size_t)NT+(size_t)t*3;
  out[ob+0]=m!=0.f?r0:0.f;
  out[ob+1]=m!=0.f?r1:0.f;
  out[ob+2]=m!=0.f?r2:0.f;
}

extern "C" void kernel_launch(void* const* d_in, const int* in_sizes, int n_in,
                              void* d_out, int out_size, void* d_ws, size_t ws_size,
                              hipStream_t stream) {
  (void)in_sizes; (void)n_in; (void)out_size;
  const float* rays_o =(const float*)d_in[0];
  const float* rays_d =(const float*)d_in[1];
  const float* pose   =(const float*)d_in[2];
  const float* dimv   =(const float*)d_in[3];
  const float* voxel  =(const float*)d_in[4];
  const float* fvol   =(const float*)d_in[5];
  const float* fvhr   =(const float*)d_in[6];
  const float* u_p    =(const float*)d_in[7];
  const float* u_cat  =(const float*)d_in[8];
  const float* u_lam  =(const float*)d_in[9];
  const float* dW1    =(const float*)d_in[10];
  const float* db1    =(const float*)d_in[11];
  const float* dW2    =(const float*)d_in[12];
  const float* db2    =(const float*)d_in[13];
  const float* rW0    =(const float*)d_in[14];
  const float* rb0    =(const float*)d_in[15];
  const float* nf_qkv =(const float*)d_in[16];
  const float* nf_qkvb=(const float*)d_in[17];
  const float* nf_o   =(const float*)d_in[18];
  const float* nf_ob  =(const float*)d_in[19];
  const float* nf_f1  =(const float*)d_in[20];
  const float* nf_f1b =(const float*)d_in[21];
  const float* nf_f2  =(const float*)d_in[22];
  const float* nf_f2b =(const float*)d_in[23];
  const float* rt_qkv =(const float*)d_in[24];
  const float* rt_qkvb=(const float*)d_in[25];
  const float* rt_o   =(const float*)d_in[26];
  const float* rt_ob  =(const float*)d_in[27];
  const float* rt_f1  =(const float*)d_in[28];
  const float* rt_f1b =(const float*)d_in[29];
  const float* rt_f2  =(const float*)d_in[30];
  const float* rt_f2b =(const float*)d_in[31];
  const float* fW     =(const float*)d_in[32];
  const float* fb     =(const float*)d_in[33];

  float* wsf=(float*)d_ws;
  short* wsb=(short*)((char*)d_ws + F32_CNT*4);
  float* out=(float*)d_out;

  // Chunking: smallest nch that fits ws_size (nch=1 measured fastest overall).
  int nch=8;
  for(int c=1;c<=8;c<<=1){
    size_t mc_=(size_t)MTOT/c;
    size_t region=mc_*640ULL; if(region<RT_TOT) region=RT_TOT;
    size_t need=F32_CNT*4 + 2ULL*(CHB + region);
    if(need <= ws_size){ nch=c; break; }
  }
  const size_t mc = (size_t)MTOT/nch;
  const int Tc = (int)(mc/8);

  short* WT  = wsb;
  short* H2  = wsb + H2OFF;
  short* arena = wsb + CHB;
  // nf chunk overlays: h0[0,128) x1[128,256) x2[512,576)
  short* o_h0 = arena;
  short* o_x1 = arena + (size_t)128*mc;
  short* o_x2 = arena + (size_t)512*mc;
  // rt overlays: qkv[0,384) att/h3[384,512) x[0,128) f1[128,384)
  short* r_qkv= arena;
  short* r_att= arena + (size_t)384*NT;
  short* r_x  = arena;
  short* r_f1 = arena + (size_t)128*NT;
  short* r_h3 = arena + (size_t)384*NT;

  k0_setup<<<NRAY/64,64,0,stream>>>(rays_o,rays_d,pose,dimv,wsf);
  k1_sample<<<NRAY,128,0,stream>>>(rays_o,rays_d,dimv,voxel,fvol,u_p,u_cat,u_lam,wsf);
  k2_sigma<<<NT,128,0,stream>>>(dW1,db1,dW2,db2,wsf,out);
  k_wprep<<<(int)((WT_TOT+255)/256),256,0,stream>>>(rW0,nf_qkv,nf_o,nf_f1,nf_f2,rt_qkv,rt_o,rt_f1,rt_f2,WT);

  const int mt=(int)(mc/128);
  const int mt32=(int)(mc/32);
  for(int ch=0; ch<nch; ++ch){
    int tok0 = ch*Tc;
    k_build<<<Tc/4,256,0,stream>>>(fvhr, wsf, o_x2, tok0);
    gemm_ln< 64,false,false,false><<<dim3(mt,1),256,0,stream>>>(o_x2, WT+WT_W0,  rb0,     nullptr, o_h0, 128);
    nf_qkv_attn_o<<<mt32,256,0,stream>>>(o_h0, WT+WT_NQKV, nf_qkvb, WT+WT_NO, nf_ob, o_x1);
    nf_f1f2<<<mt32,256,0,stream>>>(o_x1, WT+WT_NF1, nf_f1b, WT+WT_NF2, nf_f2b,
                                   H2+(size_t)tok0*128);
  }

  gemm_ln<128,true ,false,false><<<dim3(NT/128,3),256,0,stream>>>(H2,   WT+WT_RQKV,rt_qkvb, nullptr, r_qkv,384);
  rt_attn<<<NRAY*2,256,0,stream>>>(r_qkv, r_att);
  gemm_ln<128,false,false,true ><<<dim3(NT/128,1),256,0,stream>>>(r_att,WT+WT_RO,  rt_ob,   H2,      r_x,  128);
  gemm_ln<128,true ,true ,false><<<dim3(NT/128,2),256,0,stream>>>(r_x,  WT+WT_RF1, rt_f1b,  nullptr, r_f1, 256);
  gemm_ln<256,false,false,true ><<<dim3(NT/128,1),256,0,stream>>>(r_f1, WT+WT_RF2, rt_f2b,  r_x,     r_h3, 128);
  k_rad<<<NT/256,256,0,stream>>>(r_h3, fW, fb, wsf, out);
}